// Round 11
// baseline (190.585 us; speedup 1.0000x reference)
//
#include <hip/hip_runtime.h>
#include <stdint.h>

// Multi-head Hyena conv, MFMA flash-attention form, round 21:
//   S^T[m][l] = sum_d1 v[d1,m]*x1[d1,l]       mfma 16x16x16 (K=8 valid)
//   P[l][m]   = S * k[l-m]   (sliding f32x4 gate window, zero => causal)
//   O^T[d2][l] += x2 . P^T                    mfma 16x16x32 (full K=32)
// Round-21: single change vs r20: __launch_bounds__(256,4) -> (256,5).
// r20 (best, ~70.9us steady): dbuf single-barrier, 60 VGPR clean. The
// (256,5) cap is 102 VGPR -- the spill history that ruled out >=5 was on
// heavier structures (r12: ~115 live). 5 blocks/CU = 20 waves/CU (62.5%
// ceiling vs 50%), +25% independent blocks for cross-block chain overlap
// (blocks are internally lockstep but mutually independent), and ~40
// spare regs under the cap for scheduling. LDS 25.5KB x5 = 127.5 <= 160.
// Ledger: r19 16x16x16-S swap +4% (via -12 regs; MFMA cycles unchanged);
// r20 dbuf +2%; occupancy/unroll/prefetch levers all null or negative on
// heavier configs. Chain/issue-bound: MFMA 30%, true VALU ~25-30%,
// HBM 13%, ~3 waves/SIMD.
// Tripwire: WRITE>25MB = spill -> revert to (256,4). Neutral => plateau
// assessment (remaining lever = 32x32-S rewrite, est ~neutral).
// Shapes fixed by setup: B=2, D=1024, L=2048, NH=8, H=128.

typedef __attribute__((ext_vector_type(8))) short bf16x8;
typedef __attribute__((ext_vector_type(4))) short bf16x4;
typedef __attribute__((ext_vector_type(4))) float f32x4;
typedef __attribute__((ext_vector_type(2))) float f32x2;

#define NHd  8
#define SC   128     // m superchunk staged in LDS
#define GW   256     // gate window: l-m spans [l0b-s0-127, l0b-s0+127]

static __device__ __forceinline__ uint32_t pkbf(float a, float b) {
    // RNE-ish pack {bf16(a) lo, bf16(b) hi}; +0x8000 rounds (ties away)
    const uint32_t ua = __float_as_uint(a) + 0x8000u;
    const uint32_t ub = __float_as_uint(b) + 0x8000u;
    return __builtin_amdgcn_perm(ub, ua, 0x07060302u);
}

static __device__ __forceinline__ uint32_t pktr(f32x2 p) {
    // truncation pack: upper 16 bits of each f32 -> {lo,hi} bf16 (1 v_perm)
    union { f32x2 f; uint32_t u[2]; } c; c.f = p;
    return __builtin_amdgcn_perm(c.u[1], c.u[0], 0x07060302u);
}

// gate two S values by two k values: v_pk_mul_f32 + v_perm (2 inst)
static __device__ __forceinline__ uint32_t gmul2(f32x2 s, f32x2 g) {
    return pktr(s * g);
}

// S-MFMA: 16x16x16 bf16 (K=8 valid). Same C layout as 16x16x32 family.
static __device__ __forceinline__ f32x4 mfmaS(bf16x4 a, bf16x4 b, f32x4 c) {
#if __has_builtin(__builtin_amdgcn_mfma_f32_16x16x16bf16_1k)
    return __builtin_amdgcn_mfma_f32_16x16x16bf16_1k(a, b, c, 0, 0, 0);
#else
    f32x4 d;
    asm("v_mfma_f32_16x16x16_bf16 %0, %1, %2, %3"
        : "=v"(d) : "v"(a), "v"(b), "v"(c));
    return d;
#endif
}

union U8 { uint32_t u[4]; bf16x8 v; uint4 q; };
union U4 { uint32_t u[2]; bf16x4 v; };

__global__ __launch_bounds__(256, 5) void hyena_mfma21_kernel(
    const float* __restrict__ v, const float* __restrict__ kf,
    const float* __restrict__ bias, const float* __restrict__ x1,
    const float* __restrict__ x2, float* __restrict__ out,
    int B, int H, int L)
{
    __shared__ __align__(16) float4 gwin[2][GW];         // dbuf gate window
    __shared__ __align__(16) ushort vT[2][2][SC][NHd];   // [buf][b][m][d1]
    __shared__ __align__(16) ushort x2T[2][2][NHd][136]; // [buf][b][d2][pi(m)]
    __shared__ float sbuf[2][128];                       // skip gate per (b,l)

    const int tid  = threadIdx.x;
    const int h    = blockIdx.x;
    const int l0b  = ((int)gridDim.y - 1 - (int)blockIdx.y) * 128; // big-l first
    const int nk   = l0b + 128;

    const int lane = tid & 63, wv = tid >> 6;
    const int lq   = lane & 15, quad = lane >> 4;
    const int wb   = wv & 1;                // batch handled by this wave
    const int wseg = wv >> 1;               // which 64-l half of the block
    const int wl0  = l0b + wseg * 64;       // wave's 64-l range start
    const int baseb = (wb * H + h) * NHd * L;

    // ---------- fixed staging coordinates ----------
    const int sb_b   = tid >> 7, sb_row = tid & 127;
    const int sb_bs  = (sb_b * H + h) * NHd * L;
    const float* vp0 = v + sb_bs + sb_row;
    const int sb_d2  = sb_row >> 4, sb_ms = (sb_row & 15) * 8;
    const int sb_G   = sb_ms & ~31;                 // 32-group base
    const int sb_o   = sb_ms & 31;                  // 0,8,16,24
    const int sb_pa  = ((sb_o >> 2) & 3) * 8 + (sb_o >> 4) * 4;
    const float* xp0 = x2 + sb_bs + sb_d2 * L + sb_ms;
    const float* kp  = kf + h * L;
    const int gi0    = l0b - 127 + tid;             // k idx of gwin[tid] @ s0=0

    // ---------- async stage registers (one chunk in flight) ----------
    float  fv0, fv1, fv2, fv3, fv4, fv5, fv6, fv7;  // v column, 8 x d1
    float4 q0, q1;                                   // x2 8-run
    float  kg0 = 0.f, kg1 = 0.f, kg2 = 0.f, kg3 = 0.f; // gate window entry

    auto issue_stage = [&](int s0) {
        const float* vp = vp0 + s0;
        fv0 = vp[0 * L]; fv1 = vp[1 * L]; fv2 = vp[2 * L]; fv3 = vp[3 * L];
        fv4 = vp[4 * L]; fv5 = vp[5 * L]; fv6 = vp[6 * L]; fv7 = vp[7 * L];
        q0 = *(const float4*)(xp0 + s0);
        q1 = *(const float4*)(xp0 + s0 + 4);
        if (tid < GW - 1) {
            const int i = gi0 - s0;
            if (i >= 3) {
                kg0 = kp[i]; kg1 = kp[i - 1]; kg2 = kp[i - 2]; kg3 = kp[i - 3];
            } else {
                kg0 = kg1 = kg2 = kg3 = 0.f;
                if (i >= 0) kg0 = kp[i];
                if (i >= 1) kg1 = kp[i - 1];
                if (i >= 2) kg2 = kp[i - 2];
            }
        }
    };

    // ---------- prologue ----------
    issue_stage(0);   // chunk-0 loads fly under xf/sbuf build below

    // xf fragments (S-MFMA B operand, 16x16x16: k=4*(lane>>4)+i) for 4
    // l-subtiles. Quads 0-1 carry d1 = 4*quad+t; quads 2-3 zero.
    bf16x4 xf[4] = {};
    if (quad < 2) {
#pragma unroll
        for (int j = 0; j < 4; ++j) {
            float a0[4];
#pragma unroll
            for (int t = 0; t < 4; ++t)
                a0[t] = x1[baseb + (4 * quad + t) * L + wl0 + 16 * j + lq];
            U4 u0;
            u0.u[0] = pkbf(a0[0], a0[1]);
            u0.u[1] = pkbf(a0[2], a0[3]);
            xf[j] = u0.v;
        }
    }

    // skip-term gate, both b, 128 l (all 256 threads)
    {
        const int bb = tid >> 7, l = tid & 127;
        const int bs = (bb * H + h) * NHd * L;
        float s = 0.f;
#pragma unroll
        for (int d1 = 0; d1 < NHd; ++d1)
            s += bias[h * NHd + d1] * x1[bs + d1 * L + l0b + l]
                                    * v [bs + d1 * L + l0b + l];
        sbuf[bb][l] = s;
    }

    f32x4 acc[4];
#pragma unroll
    for (int j = 0; j < 4; ++j) acc[j] = (f32x4){0.f, 0.f, 0.f, 0.f};

    const int wlmax = wl0 + 63;
    // gate window coordinate (s0-independent): e = ebase - c
    const int ebase = 127 + wseg * 64 + lq - 4 * quad;

    bool gfirst = true;
    float4 g0, g1, g2, g3, g4;   // 5-deep gate file; carries across s0 too

    for (int s0 = 0, n = 0; s0 < nk; s0 += SC, ++n) {
        const int p = n & 1;

        // ---- write-late: stage regs (chunk n's data) -> buf p ----
        // WAR-safe: all waves passed barrier n-1, which follows their
        // compute n-2 (the last reader of buf p). Concurrent compute n-1
        // reads buf p^1.
        *(uint4*)&vT[p][sb_b][sb_row][0] = make_uint4(
            pkbf(fv0, fv1), pkbf(fv2, fv3), pkbf(fv4, fv5), pkbf(fv6, fv7));
        *(uint2*)&x2T[p][sb_b][sb_d2][sb_G + sb_pa] =
            make_uint2(pkbf(q0.x, q0.y), pkbf(q0.z, q0.w));
        *(uint2*)&x2T[p][sb_b][sb_d2][sb_G + sb_pa + 8] =
            make_uint2(pkbf(q1.x, q1.y), pkbf(q1.z, q1.w));
        // gwin[p][e] = {k[i],k[i-1],k[i-2],k[i-3]}, i = l0b-s0-127+e;
        // entry 255 never read (max read index 254) -> skip.
        if (tid < GW - 1)
            gwin[p][tid] = make_float4(kg0, kg1, kg2, kg3);

        // ---- issue-early: next chunk's global loads fly under compute ----
        if (s0 + SC < nk) issue_stage(s0 + SC);

        // ---- single barrier: staging visible; global loads NOT drained ----
        asm volatile("s_waitcnt lgkmcnt(0)" ::: "memory");
        __builtin_amdgcn_s_barrier();

        // wave-uniform trip count, multiple of 32 (wseg0: 64 at diagonal)
        const int cmax = min(SC, wlmax - s0 + 1);
        for (int c = 0; c < cmax; c += 32) {
            const int e = ebase - c;

            // ---- loads first (independent) ----
            // A frag (16x16x16): row=lane&15, k=4*(lane>>4)+i -> quads 0-1
            // read d1 = 4*quad..4*quad+3 (8B each); quads 2-3 zero.
            bf16x4 av0 = {}, av1 = {};
            if (quad < 2) {
                av0 = *(const bf16x4*)&vT[p][wb][c + lq][quad * 4];
                av1 = *(const bf16x4*)&vT[p][wb][c + 16 + lq][quad * 4];
            }
            // gate file: subtile j: lo = g(e+16j), hi = g(e+16j-16)
            if (gfirst) {
                g4 = *(const float4*)&gwin[p][e + 48];
                g3 = *(const float4*)&gwin[p][e + 32];
                g2 = *(const float4*)&gwin[p][e + 16];
                gfirst = false;
            } else { g4 = g2; g3 = g1; g2 = g0; }
            g1 = *(const float4*)&gwin[p][e];
            g0 = *(const float4*)&gwin[p][e - 16];
            const bf16x8 ax = *(const bf16x8*)&x2T[p][wb][lq & 7][c + 8 * quad];

            const f32x4 Z = {0.f, 0.f, 0.f, 0.f};
            // ---- subtile pair 0,1 ----
            {
                const f32x4 Sa0 = mfmaS(av0, xf[0], Z);
                const f32x4 Sa1 = mfmaS(av1, xf[0], Z);
                const f32x4 Sb0 = mfmaS(av0, xf[1], Z);
                const f32x4 Sb1 = mfmaS(av1, xf[1], Z);
                U8 p2;
                p2.u[0] = gmul2((f32x2){Sa0[0], Sa0[1]}, (f32x2){g1.x, g1.y});
                p2.u[1] = gmul2((f32x2){Sa0[2], Sa0[3]}, (f32x2){g1.z, g1.w});
                p2.u[2] = gmul2((f32x2){Sa1[0], Sa1[1]}, (f32x2){g0.x, g0.y});
                p2.u[3] = gmul2((f32x2){Sa1[2], Sa1[3]}, (f32x2){g0.z, g0.w});
                acc[0] = __builtin_amdgcn_mfma_f32_16x16x32_bf16(ax, p2.v, acc[0], 0, 0, 0);
                p2.u[0] = gmul2((f32x2){Sb0[0], Sb0[1]}, (f32x2){g2.x, g2.y});
                p2.u[1] = gmul2((f32x2){Sb0[2], Sb0[3]}, (f32x2){g2.z, g2.w});
                p2.u[2] = gmul2((f32x2){Sb1[0], Sb1[1]}, (f32x2){g1.x, g1.y});
                p2.u[3] = gmul2((f32x2){Sb1[2], Sb1[3]}, (f32x2){g1.z, g1.w});
                acc[1] = __builtin_amdgcn_mfma_f32_16x16x32_bf16(ax, p2.v, acc[1], 0, 0, 0);
            }
            // ---- subtile pair 2,3 ----
            {
                const f32x4 Sc0 = mfmaS(av0, xf[2], Z);
                const f32x4 Sc1 = mfmaS(av1, xf[2], Z);
                const f32x4 Sd0 = mfmaS(av0, xf[3], Z);
                const f32x4 Sd1 = mfmaS(av1, xf[3], Z);
                U8 p2;
                p2.u[0] = gmul2((f32x2){Sc0[0], Sc0[1]}, (f32x2){g3.x, g3.y});
                p2.u[1] = gmul2((f32x2){Sc0[2], Sc0[3]}, (f32x2){g3.z, g3.w});
                p2.u[2] = gmul2((f32x2){Sc1[0], Sc1[1]}, (f32x2){g2.x, g2.y});
                p2.u[3] = gmul2((f32x2){Sc1[2], Sc1[3]}, (f32x2){g2.z, g2.w});
                acc[2] = __builtin_amdgcn_mfma_f32_16x16x32_bf16(ax, p2.v, acc[2], 0, 0, 0);
                p2.u[0] = gmul2((f32x2){Sd0[0], Sd0[1]}, (f32x2){g4.x, g4.y});
                p2.u[1] = gmul2((f32x2){Sd0[2], Sd0[3]}, (f32x2){g4.z, g4.w});
                p2.u[2] = gmul2((f32x2){Sd1[0], Sd1[1]}, (f32x2){g3.x, g3.y});
                p2.u[3] = gmul2((f32x2){Sd1[2], Sd1[3]}, (f32x2){g3.z, g3.w});
                acc[3] = __builtin_amdgcn_mfma_f32_16x16x32_bf16(ax, p2.v, acc[3], 0, 0, 0);
            }
        }
    }

    // ---------- epilogue: O^T layout: lane (quad,lq): d2 = 4*quad+r, l = lq ----
    if (quad < 2) {
#pragma unroll
        for (int j = 0; j < 4; ++j) {
            const int lA  = wl0 + 16 * j + lq;
            const float sb = sbuf[wb][wseg * 64 + 16 * j + lq];
#pragma unroll
            for (int r = 0; r < 4; ++r) {
                const int ro = baseb + (4 * quad + r) * L + lA;
                out[ro] = acc[j][r] + x2[ro] * sb;
            }
        }
    }
}

extern "C" void kernel_launch(void* const* d_in, const int* in_sizes, int n_in,
                              void* d_out, int out_size, void* d_ws, size_t ws_size,
                              hipStream_t stream) {
    const float* v    = (const float*)d_in[0];
    const float* k    = (const float*)d_in[1];
    const float* bias = (const float*)d_in[2];
    const float* x1   = (const float*)d_in[3];
    const float* x2   = (const float*)d_in[4];
    float* out = (float*)d_out;

    const int D = in_sizes[2];            // 1024
    const int H = D / NHd;                // 128
    const int L = in_sizes[1] / H;        // 2048
    const int B = in_sizes[0] / (D * L);  // 2

    dim3 grid(H, L / 128);
    hyena_mfma21_kernel<<<grid, 256, 0, stream>>>(v, k, bias, x1, x2, out, B, H, L);
}

// Round 12
// 148.984 us; speedup vs baseline: 1.2792x; 1.2792x over previous
//
#include <hip/hip_runtime.h>
#include <stdint.h>

// Multi-head Hyena conv, MFMA flash-attention form, round 22:
//   S^T[m][l] = sum_d1 v[d1,m]*x1[d1,l]       mfma 16x16x16 (K=8 valid)
//   P[l][m]   = S * k[l-m]   (gate via padded-ks direct LDS reads)
//   O^T[d2][l] += x2 . P^T                    mfma 16x16x32 (full K=32)
// Round-22: BARRIER-FREE WAVE-PRIVATE PIPELINES. Ledger: all residency
// levers dead (5 spill cliffs; clean builds pinned 38-47% occ, 71-76us);
// per-SIMD busy ~90K cyc vs 170K wall -> 45% un-hidden chain latency,
// caused by 4-wave barrier lockstep (all waves stall together at every
// chunk rendezvous). This round removes ALL main-loop barriers:
//  1. ks2[128 zero-pad + 2048] LDS written ONCE in prologue (pad =
//     causality); gate file read directly as 8 ds_read_b32 w/ imm
//     offsets -> gwin build + kg prefetch + its sync deleted. ks2 is
//     read-only after the single prologue __syncthreads().
//  2. vT/x2T per-wave PRIVATE ([4][128][8], [4][8][136]): each wave
//     stages its own tiles (2x global loads, FETCH ~105MB, HBM <30%).
//     Same-wave RAW via in-order lgkmcnt -> zero barriers; waves drift
//     freely and hide each other's stalls. Single buffer (dbuf existed
//     only for cross-wave WAR). LDS 26.6KB.
//  3. Carried: (256,4), 16x16x16 S (r19), write-late/issue-early stage
//     regs, carried gate file, rolling loop, v_pk_mul+v_perm gating.
// Tripwire: WRITE>25MB = spill -> revert to r20. Clean-but-neutral =>
// intrinsic chain plateau.
// Shapes fixed by setup: B=2, D=1024, L=2048, NH=8, H=128.

typedef __attribute__((ext_vector_type(8))) short bf16x8;
typedef __attribute__((ext_vector_type(4))) short bf16x4;
typedef __attribute__((ext_vector_type(4))) float f32x4;
typedef __attribute__((ext_vector_type(2))) float f32x2;

#define NHd  8
#define SC   128     // m superchunk staged in LDS
#define KPAD 128     // ks2 zero pad (causality: k[j<0] = 0)

static __device__ __forceinline__ uint32_t pkbf(float a, float b) {
    // RNE-ish pack {bf16(a) lo, bf16(b) hi}; +0x8000 rounds (ties away)
    const uint32_t ua = __float_as_uint(a) + 0x8000u;
    const uint32_t ub = __float_as_uint(b) + 0x8000u;
    return __builtin_amdgcn_perm(ub, ua, 0x07060302u);
}

static __device__ __forceinline__ uint32_t pktr(f32x2 p) {
    // truncation pack: upper 16 bits of each f32 -> {lo,hi} bf16 (1 v_perm)
    union { f32x2 f; uint32_t u[2]; } c; c.f = p;
    return __builtin_amdgcn_perm(c.u[1], c.u[0], 0x07060302u);
}

// gate two S values by two k values: v_pk_mul_f32 + v_perm (2 inst)
static __device__ __forceinline__ uint32_t gmul2(f32x2 s, f32x2 g) {
    return pktr(s * g);
}

// S-MFMA: 16x16x16 bf16 (K=8 valid). Same C layout as 16x16x32 family.
static __device__ __forceinline__ f32x4 mfmaS(bf16x4 a, bf16x4 b, f32x4 c) {
#if __has_builtin(__builtin_amdgcn_mfma_f32_16x16x16bf16_1k)
    return __builtin_amdgcn_mfma_f32_16x16x16bf16_1k(a, b, c, 0, 0, 0);
#else
    f32x4 d;
    asm("v_mfma_f32_16x16x16_bf16 %0, %1, %2, %3"
        : "=v"(d) : "v"(a), "v"(b), "v"(c));
    return d;
#endif
}

union U8 { uint32_t u[4]; bf16x8 v; uint4 q; };
union U4 { uint32_t u[2]; bf16x4 v; };

// gate quad from ks2 base pointer at relative offset R:
//   {kb[R], kb[R-1], kb[R-2], kb[R-3]}
#define GQUAD(kb, R) make_float4((kb)[(R)], (kb)[(R)-1], (kb)[(R)-2], (kb)[(R)-3])

__global__ __launch_bounds__(256, 4) void hyena_mfma22_kernel(
    const float* __restrict__ v, const float* __restrict__ kf,
    const float* __restrict__ bias, const float* __restrict__ x1,
    const float* __restrict__ x2, float* __restrict__ out,
    int B, int H, int L)
{
    __shared__ __align__(16) float  ks2[KPAD + 2048];   // zero pad + k[h,:]
    __shared__ __align__(16) ushort vTw[4][SC][NHd];    // per-wave [m][d1]
    __shared__ __align__(16) ushort x2Tw[4][NHd][136];  // per-wave [d2][pi(m)]
    __shared__ float sbuf[2][128];                      // skip gate per (b,l)

    const int tid  = threadIdx.x;
    const int h    = blockIdx.x;
    const int l0b  = ((int)gridDim.y - 1 - (int)blockIdx.y) * 128; // big-l first
    const int nk   = l0b + 128;

    const int lane = tid & 63, wv = tid >> 6;
    const int lq   = lane & 15, quad = lane >> 4;
    const int wb   = wv & 1;                // batch handled by this wave
    const int wseg = wv >> 1;               // which 64-l half of the block
    const int wl0  = l0b + wseg * 64;       // wave's 64-l range start
    const int baseb = (wb * H + h) * NHd * L;

    // ---------- per-wave staging coordinates (rows lane, lane+64) ----------
    const float* vpw = v + baseb + lane;            // + s0 + {0,64} per row
    const int d2A = lane >> 4;                      // rr = lane
    const int d2B = d2A + 4;                        // rr = lane + 64
    const int ms  = (lane & 15) * 8;
    const int G   = ms & ~31;                       // 32-group base
    const int o   = ms & 31;                        // 0,8,16,24
    const int pa  = ((o >> 2) & 3) * 8 + (o >> 4) * 4;
    const float* xpA = x2 + baseb + d2A * L + ms;   // + s0
    const float* xpB = x2 + baseb + d2B * L + ms;

    // ---------- async stage registers (one chunk in flight, per wave) ------
    float  fA0, fA1, fA2, fA3, fA4, fA5, fA6, fA7;  // v col, row lane
    float  fB0, fB1, fB2, fB3, fB4, fB5, fB6, fB7;  // v col, row lane+64
    float4 qA0, qA1, qB0, qB1;                      // x2 8-runs

    auto issue_stage = [&](int s0) {
        const float* va = vpw + s0;
        fA0 = va[0 * L]; fA1 = va[1 * L]; fA2 = va[2 * L]; fA3 = va[3 * L];
        fA4 = va[4 * L]; fA5 = va[5 * L]; fA6 = va[6 * L]; fA7 = va[7 * L];
        const float* vb = va + 64;
        fB0 = vb[0 * L]; fB1 = vb[1 * L]; fB2 = vb[2 * L]; fB3 = vb[3 * L];
        fB4 = vb[4 * L]; fB5 = vb[5 * L]; fB6 = vb[6 * L]; fB7 = vb[7 * L];
        qA0 = *(const float4*)(xpA + s0);
        qA1 = *(const float4*)(xpA + s0 + 4);
        qB0 = *(const float4*)(xpB + s0);
        qB1 = *(const float4*)(xpB + s0 + 4);
    };

    // ---------- prologue ----------
    issue_stage(0);   // chunk-0 loads fly under ks2/xf/sbuf build below

    // ks2: zero pad + full k prefix (read-only after the one barrier)
    for (int idx = tid; idx < KPAD + 2048; idx += 256)
        ks2[idx] = (idx < KPAD || idx - KPAD >= L) ? 0.f : kf[h * L + idx - KPAD];

    // xf fragments (S-MFMA B operand, 16x16x16: k=4*(lane>>4)+i) for 4
    // l-subtiles. Quads 0-1 carry d1 = 4*quad+t; quads 2-3 zero.
    bf16x4 xf[4] = {};
    if (quad < 2) {
#pragma unroll
        for (int j = 0; j < 4; ++j) {
            float a0[4];
#pragma unroll
            for (int t = 0; t < 4; ++t)
                a0[t] = x1[baseb + (4 * quad + t) * L + wl0 + 16 * j + lq];
            U4 u0;
            u0.u[0] = pkbf(a0[0], a0[1]);
            u0.u[1] = pkbf(a0[2], a0[3]);
            xf[j] = u0.v;
        }
    }

    // skip-term gate, both b, 128 l (all 256 threads)
    {
        const int bb = tid >> 7, l = tid & 127;
        const int bs = (bb * H + h) * NHd * L;
        float s = 0.f;
#pragma unroll
        for (int d1 = 0; d1 < NHd; ++d1)
            s += bias[h * NHd + d1] * x1[bs + d1 * L + l0b + l]
                                    * v [bs + d1 * L + l0b + l];
        sbuf[bb][l] = s;
    }

    // The ONLY block-wide barrier: ks2 + sbuf visible to all waves.
    __syncthreads();

    f32x4 acc[4];
#pragma unroll
    for (int j = 0; j < 4; ++j) acc[j] = (f32x4){0.f, 0.f, 0.f, 0.f};

    const int wlmax = wl0 + 63;
    // gate coordinate: ks2 index of g1.x at iter c is ibase - c
    const int ebase = 127 + wseg * 64 + lq - 4 * quad;

    bool gfirst = true;
    float4 g0, g1, g2, g3, g4;   // 5-deep gate file; carries across s0 too

    for (int s0 = 0; s0 < nk; s0 += SC) {
        // ---- write-late: stage regs (this chunk) -> PRIVATE tiles ----
        // Same-wave RAW (ds_write -> ds_read below) ordered by lgkmcnt;
        // no cross-wave hazard: buffers are wave-private.
        *(uint4*)&vTw[wv][lane][0] = make_uint4(
            pkbf(fA0, fA1), pkbf(fA2, fA3), pkbf(fA4, fA5), pkbf(fA6, fA7));
        *(uint4*)&vTw[wv][lane + 64][0] = make_uint4(
            pkbf(fB0, fB1), pkbf(fB2, fB3), pkbf(fB4, fB5), pkbf(fB6, fB7));
        *(uint2*)&x2Tw[wv][d2A][G + pa] =
            make_uint2(pkbf(qA0.x, qA0.y), pkbf(qA0.z, qA0.w));
        *(uint2*)&x2Tw[wv][d2A][G + pa + 8] =
            make_uint2(pkbf(qA1.x, qA1.y), pkbf(qA1.z, qA1.w));
        *(uint2*)&x2Tw[wv][d2B][G + pa] =
            make_uint2(pkbf(qB0.x, qB0.y), pkbf(qB0.z, qB0.w));
        *(uint2*)&x2Tw[wv][d2B][G + pa + 8] =
            make_uint2(pkbf(qB1.x, qB1.y), pkbf(qB1.z, qB1.w));

        // ---- issue-early: next chunk's global loads fly under compute ----
        if (s0 + SC < nk) issue_stage(s0 + SC);

        // gate base for this chunk: ks2 index of g1.x at c=0
        const float* kb0 = &ks2[KPAD + l0b - s0 - 127 + ebase];

        // wave-uniform trip count, multiple of 32 (wseg0: 64 at diagonal)
        const int cmax = min(SC, wlmax - s0 + 1);
        for (int c = 0; c < cmax; c += 32) {
            const float* kb = kb0 - c;

            // ---- loads first (independent) ----
            // A frag (16x16x16): quads 0-1 read d1 = 4*quad..+3 (8B each).
            bf16x4 av0 = {}, av1 = {};
            if (quad < 2) {
                av0 = *(const bf16x4*)&vTw[wv][c + lq][quad * 4];
                av1 = *(const bf16x4*)&vTw[wv][c + 16 + lq][quad * 4];
            }
            // gate file: fresh g1/g0 each iter; g4..g2 rotate (ks2 is
            // read-only => identical values regardless of chunk/drift).
            if (gfirst) {
                g4 = GQUAD(kb, 48);
                g3 = GQUAD(kb, 32);
                g2 = GQUAD(kb, 16);
                gfirst = false;
            } else { g4 = g2; g3 = g1; g2 = g0; }
            g1 = GQUAD(kb, 0);
            g0 = GQUAD(kb, -16);
            const bf16x8 ax = *(const bf16x8*)&x2Tw[wv][lq & 7][c + 8 * quad];

            const f32x4 Z = {0.f, 0.f, 0.f, 0.f};
            // ---- subtile pair 0,1 ----
            {
                const f32x4 Sa0 = mfmaS(av0, xf[0], Z);
                const f32x4 Sa1 = mfmaS(av1, xf[0], Z);
                const f32x4 Sb0 = mfmaS(av0, xf[1], Z);
                const f32x4 Sb1 = mfmaS(av1, xf[1], Z);
                U8 p2;
                p2.u[0] = gmul2((f32x2){Sa0[0], Sa0[1]}, (f32x2){g1.x, g1.y});
                p2.u[1] = gmul2((f32x2){Sa0[2], Sa0[3]}, (f32x2){g1.z, g1.w});
                p2.u[2] = gmul2((f32x2){Sa1[0], Sa1[1]}, (f32x2){g0.x, g0.y});
                p2.u[3] = gmul2((f32x2){Sa1[2], Sa1[3]}, (f32x2){g0.z, g0.w});
                acc[0] = __builtin_amdgcn_mfma_f32_16x16x32_bf16(ax, p2.v, acc[0], 0, 0, 0);
                p2.u[0] = gmul2((f32x2){Sb0[0], Sb0[1]}, (f32x2){g2.x, g2.y});
                p2.u[1] = gmul2((f32x2){Sb0[2], Sb0[3]}, (f32x2){g2.z, g2.w});
                p2.u[2] = gmul2((f32x2){Sb1[0], Sb1[1]}, (f32x2){g1.x, g1.y});
                p2.u[3] = gmul2((f32x2){Sb1[2], Sb1[3]}, (f32x2){g1.z, g1.w});
                acc[1] = __builtin_amdgcn_mfma_f32_16x16x32_bf16(ax, p2.v, acc[1], 0, 0, 0);
            }
            // ---- subtile pair 2,3 ----
            {
                const f32x4 Sc0 = mfmaS(av0, xf[2], Z);
                const f32x4 Sc1 = mfmaS(av1, xf[2], Z);
                const f32x4 Sd0 = mfmaS(av0, xf[3], Z);
                const f32x4 Sd1 = mfmaS(av1, xf[3], Z);
                U8 p2;
                p2.u[0] = gmul2((f32x2){Sc0[0], Sc0[1]}, (f32x2){g3.x, g3.y});
                p2.u[1] = gmul2((f32x2){Sc0[2], Sc0[3]}, (f32x2){g3.z, g3.w});
                p2.u[2] = gmul2((f32x2){Sc1[0], Sc1[1]}, (f32x2){g2.x, g2.y});
                p2.u[3] = gmul2((f32x2){Sc1[2], Sc1[3]}, (f32x2){g2.z, g2.w});
                acc[2] = __builtin_amdgcn_mfma_f32_16x16x32_bf16(ax, p2.v, acc[2], 0, 0, 0);
                p2.u[0] = gmul2((f32x2){Sd0[0], Sd0[1]}, (f32x2){g4.x, g4.y});
                p2.u[1] = gmul2((f32x2){Sd0[2], Sd0[3]}, (f32x2){g4.z, g4.w});
                p2.u[2] = gmul2((f32x2){Sd1[0], Sd1[1]}, (f32x2){g3.x, g3.y});
                p2.u[3] = gmul2((f32x2){Sd1[2], Sd1[3]}, (f32x2){g3.z, g3.w});
                acc[3] = __builtin_amdgcn_mfma_f32_16x16x32_bf16(ax, p2.v, acc[3], 0, 0, 0);
            }
        }
    }

    // ---------- epilogue: O^T layout: lane (quad,lq): d2 = 4*quad+r, l = lq ----
    if (quad < 2) {
#pragma unroll
        for (int j = 0; j < 4; ++j) {
            const int lA  = wl0 + 16 * j + lq;
            const float sb = sbuf[wb][wseg * 64 + 16 * j + lq];
#pragma unroll
            for (int r = 0; r < 4; ++r) {
                const int ro = baseb + (4 * quad + r) * L + lA;
                out[ro] = acc[j][r] + x2[ro] * sb;
            }
        }
    }
}

extern "C" void kernel_launch(void* const* d_in, const int* in_sizes, int n_in,
                              void* d_out, int out_size, void* d_ws, size_t ws_size,
                              hipStream_t stream) {
    const float* v    = (const float*)d_in[0];
    const float* k    = (const float*)d_in[1];
    const float* bias = (const float*)d_in[2];
    const float* x1   = (const float*)d_in[3];
    const float* x2   = (const float*)d_in[4];
    float* out = (float*)d_out;

    const int D = in_sizes[2];            // 1024
    const int H = D / NHd;                // 128
    const int L = in_sizes[1] / H;        // 2048
    const int B = in_sizes[0] / (D * L);  // 2

    dim3 grid(H, L / 128);
    hyena_mfma22_kernel<<<grid, 256, 0, stream>>>(v, k, bias, x1, x2, out, B, H, L);
}